// Round 4
// baseline (4932.734 us; speedup 1.0000x reference)
//
#include <hip/hip_runtime.h>

#define BB 128
#define CH 16
#define NBANDS 100
#define OUTC 10

// L1 padded fp32 geometry (single channel): [12 e][12 f][11 g][11 h]
#define P1PLANE 121
#define P1POS   17424

// conv_mfma LDS tile: 12 (e',f') planes x [11 g][16 h] x 16ci bf16 (+swizzle)
#define LPLANE  (11*16*32)     /* 5632 B per plane */
#define LDSTILE (12*LPLANE)    /* 67584 B */
#define NPAIR   14             /* 27 (de,df,dg) combos -> 14 pairs (last half dummy) */

typedef unsigned short ushort_t;
typedef unsigned int uint_t;
typedef __attribute__((ext_vector_type(8))) short short8;
typedef __attribute__((ext_vector_type(4))) float f32x4;

__device__ __forceinline__ ushort_t f2bf(float f) {
    unsigned u = __float_as_uint(f);
    unsigned r = u + 0x7fffu + ((u >> 16) & 1u);   // RNE
    return (ushort_t)(r >> 16);
}
__device__ __forceinline__ float bf2f(ushort_t u) {
    return __uint_as_float((uint_t)u << 16);
}
// swizzle byte addr: XOR bits[5:4] with bits[8:7] -> 2-way (free) bank pattern
__device__ __forceinline__ int swz(int x) { return x ^ ((x >> 3) & 0x30); }

// DPP shift within 16-lane rows. row_shr:1 (0x111): dst[n]=src[n-1]; row_shl:1 (0x101): dst[n]=src[n+1]
template<int CTRL>
__device__ __forceinline__ short8 dpp_shift(short8 v) {
    union { short8 s; int i[4]; } a, b;
    a.s = v;
    #pragma unroll
    for (int k = 0; k < 4; ++k)
        b.i[k] = __builtin_amdgcn_update_dpp(0, a.i[k], CTRL, 0xf, 0xf, true);
    return b.s;
}

// ---------------- prep: local = x - center -> padded fp32 single-channel ----------------
__global__ void prep_kernel(const float* __restrict__ x, float* __restrict__ bufP) {
    int idx = blockIdx.x * 256 + threadIdx.x;
    if (idx >= BB * NBANDS * 81) return;
    int s = idx % 81;
    int p = (idx / 81) % NBANDS;
    int b = idx / (81 * NBANDS);
    int e = p / 10, f = p % 10, g = s / 9, h = s % 9;
    const float* xp = x + ((size_t)b * NBANDS + p) * 81;
    float v = xp[s] - xp[40];
    bufP[(size_t)b * P1POS + ((e + 1) * 12 + (f + 1)) * P1PLANE + (g + 1) * 11 + (h + 1)] = v;
}

// ---------------- pack weights: [14 pair][3 dh][64 lane] x 16B B-frags ----------------
__global__ void pack_w_kernel(const float* __restrict__ w, uint4* __restrict__ wp) {
    int t = blockIdx.x * 256 + threadIdx.x;
    if (t >= NPAIR * 3 * 64) return;
    int l = t & 63, pd = t >> 6;
    int p = pd / 3, dh = pd % 3;
    int co = l & 15, kh = l >> 4;
    int m = kh >> 1, cih = (kh & 1) * 8;
    int c = 2 * p + m;
    uint_t r[4] = {0, 0, 0, 0};
    if (c <= 26) {
        int tap = c * 3 + dh;   // (de*9+df*3+dg)*3+dh = de*27+df*9+dg*3+dh
        #pragma unroll
        for (int jj = 0; jj < 4; ++jj) {
            ushort_t lo = f2bf(w[(co * 16 + cih + 2 * jj) * 81 + tap]);
            ushort_t hi = f2bf(w[(co * 16 + cih + 2 * jj + 1) * 81 + tap]);
            r[jj] = (uint_t)lo | ((uint_t)hi << 16);
        }
    }
    uint4 q; q.x = r[0]; q.y = r[1]; q.z = r[2]; q.w = r[3];
    wp[t] = q;
}

// ---------------- L1: cin=1 fp32 conv -> compact bf16 [b][ef][gh][16ci] ----------------
__global__ __launch_bounds__(256) void conv1_kernel(
    const float* __restrict__ in, const float* __restrict__ w,
    const float* __restrict__ bias, ushort_t* __restrict__ out) {
    int idx = blockIdx.x * 256 + threadIdx.x;
    if (idx >= 900) return;
    int b = blockIdx.z;
    int co0 = blockIdx.y * 8;
    int g = idx % 9;
    int f = (idx / 9) % 10;
    int e = idx / 90;

    float acc[8][9];
    #pragma unroll
    for (int co = 0; co < 8; ++co) {
        float bv = bias[co0 + co];
        #pragma unroll
        for (int h = 0; h < 9; ++h) acc[co][h] = bv;
    }

    const float* ip = in + (size_t)b * P1POS;
    #pragma unroll
    for (int de = 0; de < 3; ++de)
    #pragma unroll
    for (int df = 0; df < 3; ++df)
    #pragma unroll
    for (int dg = 0; dg < 3; ++dg) {
        const float* rp = ip + ((e + de) * 12 + (f + df)) * P1PLANE + (g + dg) * 11;
        float v[11];
        #pragma unroll
        for (int k = 0; k < 11; ++k) v[k] = rp[k];
        #pragma unroll
        for (int dh = 0; dh < 3; ++dh) {
            int tap = de * 27 + df * 9 + dg * 3 + dh;
            #pragma unroll
            for (int co = 0; co < 8; ++co) {
                float ws = w[(co0 + co) * 81 + tap];
                #pragma unroll
                for (int h = 0; h < 9; ++h)
                    acc[co][h] = fmaf(ws, v[h + dh], acc[co][h]);
            }
        }
    }

    ushort_t* op = out + ((size_t)b * NBANDS + e * 10 + f) * 81 * 16 + g * 9 * 16 + co0;
    #pragma unroll
    for (int h = 0; h < 9; ++h) {
        uint4 q;
        q.x = (uint_t)f2bf(fmaxf(acc[0][h], 0.f)) | ((uint_t)f2bf(fmaxf(acc[1][h], 0.f)) << 16);
        q.y = (uint_t)f2bf(fmaxf(acc[2][h], 0.f)) | ((uint_t)f2bf(fmaxf(acc[3][h], 0.f)) << 16);
        q.z = (uint_t)f2bf(fmaxf(acc[4][h], 0.f)) | ((uint_t)f2bf(fmaxf(acc[5][h], 0.f)) << 16);
        q.w = (uint_t)f2bf(fmaxf(acc[6][h], 0.f)) | ((uint_t)f2bf(fmaxf(acc[7][h], 0.f)) << 16);
        *(uint4*)(op + h * 16) = q;
    }
}

// ---------------- MFMA conv: DPP dh-sharing, compact bf16 in/out ----------------
// in/out: [b][100 ef][81 gh][16 ci] bf16. wp: [14][3][64] 16B frags. block = (b, e, f-pair), 384 thr.
__global__ __launch_bounds__(384, 3) void conv_mfma_kernel(
    const ushort_t* __restrict__ in, const uint4* __restrict__ wp,
    const float* __restrict__ bias, ushort_t* __restrict__ out) {

    __shared__ __align__(16) char sIn[LDSTILE];

    int tid = threadIdx.x;
    int bid = blockIdx.x;
    // batch->XCD affinity: blocks of one batch land on one XCD (round-robin heuristic)
    int xcd = bid & 7;
    int j8 = bid >> 3;                 // 0..799
    int b = xcd * 16 + (j8 / 50);
    int t50 = j8 % 50;
    int e = t50 / 5;
    int f0 = (t50 % 5) * 2;

    // ---- stage: one pass writes every LDS chunk (interior data or zero pad) ----
    const ushort_t* gin = in + (size_t)b * (NBANDS * 81 * 16);
    #pragma unroll 1
    for (int i = tid; i < LDSTILE / 16; i += 384) {    // 4224 chunks, 11 iters exact
        int half = i & 1;
        int h_l = (i >> 1) & 15;
        int glp = i >> 5;              // pl*11 + g_l
        int g_l = glp % 11;
        int pl = glp / 11;
        uint4 val = make_uint4(0, 0, 0, 0);
        int ep = e - 1 + (pl >> 2);
        int fp = f0 - 1 + (pl & 3);
        int g = g_l - 1, h = h_l - 1;
        if ((unsigned)ep < 10 && (unsigned)fp < 10 && (unsigned)g < 9 && (unsigned)h < 9)
            val = *(const uint4*)(gin + (size_t)((ep * 10 + fp) * 81 + g * 9 + h) * 16 + half * 8);
        *(uint4*)(sIn + swz(i * 16)) = val;
    }
    __syncthreads();

    int l = tid & 63;
    int wv = tid >> 6;                 // 0..5
    int r = l & 15;                    // h_lds row
    int kh = l >> 4;
    int m = kh >> 1;                   // K-pair member
    int laneBase = r * 32 + (kh & 1) * 16;

    // wave's 3 tiles: ids wv, wv+6, wv+12 of 18 (j = id/9, g = id%9)
    int id0 = wv, id1 = wv + 6, id2 = wv + 12;
    int tc0 = (id0 / 9) * LPLANE + (id0 % 9) * 512 + laneBase;
    int tc1 = (id1 / 9) * LPLANE + (id1 % 9) * 512 + laneBase;
    int tc2 = (id2 / 9) * LPLANE + (id2 % 9) * 512 + laneBase;

    float bv = bias[l & 15];
    f32x4 acc0 = {bv, bv, bv, bv}, acc1 = acc0, acc2 = acc0;

    const short8* wv8 = (const short8*)wp;

    #pragma unroll
    for (int p = 0; p < NPAIR; ++p) {
        int c = 2 * p + m; if (c > 26) c = 26;       // dummy member -> valid addr, zero weights
        int de = c / 9, df = (c / 3) % 3, dg = c % 3;
        int offp = (de * 4 + df) * LPLANE + dg * 512;

        short8 B0 = wv8[(p * 3 + 0) * 64 + l];
        short8 B1 = wv8[(p * 3 + 1) * 64 + l];
        short8 B2 = wv8[(p * 3 + 2) * 64 + l];

        short8 a1 = *(const short8*)(sIn + swz(offp + tc0));
        short8 a0 = dpp_shift<0x111>(a1);            // dh=0: in(h-1)
        short8 a2 = dpp_shift<0x101>(a1);            // dh=2: in(h+1)
        acc0 = __builtin_amdgcn_mfma_f32_16x16x32_bf16(a0, B0, acc0, 0, 0, 0);
        acc0 = __builtin_amdgcn_mfma_f32_16x16x32_bf16(a1, B1, acc0, 0, 0, 0);
        acc0 = __builtin_amdgcn_mfma_f32_16x16x32_bf16(a2, B2, acc0, 0, 0, 0);

        short8 b1f = *(const short8*)(sIn + swz(offp + tc1));
        short8 b0f = dpp_shift<0x111>(b1f);
        short8 b2f = dpp_shift<0x101>(b1f);
        acc1 = __builtin_amdgcn_mfma_f32_16x16x32_bf16(b0f, B0, acc1, 0, 0, 0);
        acc1 = __builtin_amdgcn_mfma_f32_16x16x32_bf16(b1f, B1, acc1, 0, 0, 0);
        acc1 = __builtin_amdgcn_mfma_f32_16x16x32_bf16(b2f, B2, acc1, 0, 0, 0);

        short8 c1f = *(const short8*)(sIn + swz(offp + tc2));
        short8 c0f = dpp_shift<0x111>(c1f);
        short8 c2f = dpp_shift<0x101>(c1f);
        acc2 = __builtin_amdgcn_mfma_f32_16x16x32_bf16(c0f, B0, acc2, 0, 0, 0);
        acc2 = __builtin_amdgcn_mfma_f32_16x16x32_bf16(c1f, B1, acc2, 0, 0, 0);
        acc2 = __builtin_amdgcn_mfma_f32_16x16x32_bf16(c2f, B2, acc2, 0, 0, 0);
    }

    // ---- store: D col = lane&15 = co, rows = kh*4+reg = h_lds; keep h_lds 1..9 ----
    ushort_t* gout = out + (size_t)b * (NBANDS * 81 * 16);
    int co = l & 15;
    {
        int jj = id0 / 9, g = id0 % 9;
        int base = ((e * 10 + f0 + jj) * 81 + g * 9) * 16 + co;
        #pragma unroll
        for (int reg = 0; reg < 4; ++reg) {
            int rr = kh * 4 + reg;
            if (rr >= 1 && rr <= 9) gout[base + (rr - 1) * 16] = f2bf(fmaxf(acc0[reg], 0.f));
        }
    }
    {
        int jj = id1 / 9, g = id1 % 9;
        int base = ((e * 10 + f0 + jj) * 81 + g * 9) * 16 + co;
        #pragma unroll
        for (int reg = 0; reg < 4; ++reg) {
            int rr = kh * 4 + reg;
            if (rr >= 1 && rr <= 9) gout[base + (rr - 1) * 16] = f2bf(fmaxf(acc1[reg], 0.f));
        }
    }
    {
        int jj = id2 / 9, g = id2 % 9;
        int base = ((e * 10 + f0 + jj) * 81 + g * 9) * 16 + co;
        #pragma unroll
        for (int reg = 0; reg < 4; ++reg) {
            int rr = kh * 4 + reg;
            if (rr >= 1 && rr <= 9) gout[base + (rr - 1) * 16] = f2bf(fmaxf(acc2[reg], 0.f));
        }
    }
}

// ---------------- feat = mean over ef: compact bf16 -> fp32 [b][c][81] ----------------
__global__ void feat_kernel(const ushort_t* __restrict__ a, float* __restrict__ feat) {
    int idx = blockIdx.x * 256 + threadIdx.x;
    if (idx >= BB * CH * 81) return;
    int c = idx & 15;
    int gh = (idx >> 4) % 81;
    int b = idx / (81 * 16);
    const ushort_t* ap = a + (size_t)b * (NBANDS * 81 * 16) + gh * 16 + c;
    float s = 0.f;
    #pragma unroll
    for (int ef = 0; ef < 100; ++ef) s += bf2f(ap[(size_t)ef * 81 * 16]);
    feat[((size_t)b * CH + c) * 81 + gh] = s * 0.01f;
}

// ---------------- fc ----------------
__global__ void fc_kernel(const float* __restrict__ feat, const float* __restrict__ fcw,
                          const float* __restrict__ fcb, float* __restrict__ out) {
    int idx = blockIdx.x * 256 + threadIdx.x;
    if (idx >= BB * OUTC * 81) return;
    int s = idx % 81;
    int o = (idx / 81) % OUTC;
    int b = idx / (81 * OUTC);
    const float* fp = feat + (size_t)b * CH * 81 + s;
    float acc = fcb[o];
    #pragma unroll
    for (int c = 0; c < CH; ++c) acc += fcw[o * CH + c] * fp[c * 81];
    out[idx] = acc;
}

extern "C" void kernel_launch(void* const* d_in, const int* in_sizes, int n_in,
                              void* d_out, int out_size, void* d_ws, size_t ws_size,
                              hipStream_t stream) {
    const float* x   = (const float*)d_in[0];
    const float* w1  = (const float*)d_in[1];
    const float* b1  = (const float*)d_in[2];
    const float* w2  = (const float*)d_in[3];
    const float* b2  = (const float*)d_in[4];
    const float* w3  = (const float*)d_in[5];
    const float* b3  = (const float*)d_in[6];
    const float* w4  = (const float*)d_in[7];
    const float* b4  = (const float*)d_in[8];
    const float* w5  = (const float*)d_in[9];
    const float* b5  = (const float*)d_in[10];
    const float* fcw = (const float*)d_in[11];
    const float* fcb = (const float*)d_in[12];
    float* outp = (float*)d_out;

    // ---- ws layout ----
    char* wsc = (char*)d_ws;
    const size_t WPL = (size_t)NPAIR * 3 * 64;            // uint4 per layer = 2688
    uint4* wp_all = (uint4*)wsc;
    size_t off = 4 * WPL * sizeof(uint4);                  // 172032 B
    float* bufP = (float*)(wsc + off);  off += (size_t)BB * P1POS * 4;          // 8.92 MB
    float* featb = (float*)(wsc + off); off += (size_t)BB * CH * 81 * 4;        // 0.66 MB
    ushort_t* actA = (ushort_t*)(wsc + off); off += (size_t)BB * NBANDS * 81 * 16 * 2;  // 33.2 MB
    ushort_t* actB = (ushort_t*)(wsc + off);

    // ---- pack weights for L2..L5 ----
    const float* ws_[4] = {w2, w3, w4, w5};
    for (int i = 0; i < 4; ++i)
        pack_w_kernel<<<(NPAIR * 3 * 64 + 255) / 256, 256, 0, stream>>>(ws_[i], wp_all + i * WPL);

    // ---- zero L1 padded buffer (pads must be 0; interior overwritten every call) ----
    hipMemsetAsync(bufP, 0, (size_t)BB * P1POS * 4, stream);

    int pt = BB * NBANDS * 81;
    prep_kernel<<<(pt + 255) / 256, 256, 0, stream>>>(x, bufP);

    dim3 c1g(4, 2, BB);
    conv1_kernel<<<c1g, 256, 0, stream>>>(bufP, w1, b1, actA);

    conv_mfma_kernel<<<6400, 384, 0, stream>>>(actA, wp_all + 0 * WPL, b2, actB);
    conv_mfma_kernel<<<6400, 384, 0, stream>>>(actB, wp_all + 1 * WPL, b3, actA);
    conv_mfma_kernel<<<6400, 384, 0, stream>>>(actA, wp_all + 2 * WPL, b4, actB);
    conv_mfma_kernel<<<6400, 384, 0, stream>>>(actB, wp_all + 3 * WPL, b5, actA);

    int ft = BB * CH * 81;
    feat_kernel<<<(ft + 255) / 256, 256, 0, stream>>>(actA, featb);

    int ot = BB * OUTC * 81;
    fc_kernel<<<(ot + 255) / 256, 256, 0, stream>>>(featb, fcw, fcb, outp);
}

// Round 5
// 4134.050 us; speedup vs baseline: 1.1932x; 1.1932x over previous
//
#include <hip/hip_runtime.h>

#define BB 128
#define CH 16
#define NBANDS 100
#define OUTC 10

// padded fp32 activations: [12 e'][12 f'][11 g'][11 h'] (x16 ci for conv buffers)
// valid data at e',f' in [1,10], g',h' in [1,9]; pads of 16ci buffers are NEVER read.
#define P1PLANE 121
#define P1POS   17424   /* 12*12*121 */

// LDS tile: [12 pl = 4e' x 3f'][11 g][16 h][16 ci bf16] = 67584 B
#define LPLANE  5632        /* 11*16*32 B */
#define LDSTILE (12*LPLANE) /* 67584 B */
#define NPAIR   14          /* 27 (de,df,dg) combos -> 14 K=32 pairs (last half dummy) */

typedef unsigned short ushort_t;
typedef unsigned int uint_t;
typedef __attribute__((ext_vector_type(8))) short short8;
typedef __attribute__((ext_vector_type(4))) float f32x4;

__device__ __forceinline__ ushort_t f2bf(float f) {
    unsigned u = __float_as_uint(f);
    unsigned r = u + 0x7fffu + ((u >> 16) & 1u);   // RNE
    return (ushort_t)(r >> 16);
}
__device__ __forceinline__ uint_t pk2(float a, float b) {
    return (uint_t)f2bf(a) | ((uint_t)f2bf(b) << 16);
}

// DPP shift within 16-lane rows. row_shr:1 (0x111): dst[n]=src[n-1]; row_shl:1 (0x101): dst[n]=src[n+1]
template<int CTRL>
__device__ __forceinline__ short8 dpp_shift(short8 v) {
    union { short8 s; int i[4]; } a, b;
    a.s = v;
    #pragma unroll
    for (int k = 0; k < 4; ++k)
        b.i[k] = __builtin_amdgcn_update_dpp(0, a.i[k], CTRL, 0xf, 0xf, true);
    return b.s;
}

// ---------------- prep: local = x - center -> padded fp32 single-channel ----------------
__global__ void prep_kernel(const float* __restrict__ x, float* __restrict__ bufP, int nb) {
    int idx = blockIdx.x * 256 + threadIdx.x;
    if (idx >= nb * NBANDS * 81) return;
    int s = idx % 81;
    int p = (idx / 81) % NBANDS;
    int b = idx / (81 * NBANDS);
    int e = p / 10, f = p % 10, g = s / 9, h = s % 9;
    const float* xp = x + ((size_t)b * NBANDS + p) * 81;
    float v = xp[s] - xp[40];
    bufP[(size_t)b * P1POS + ((e + 1) * 12 + (f + 1)) * P1PLANE + (g + 1) * 11 + (h + 1)] = v;
}

// ---------------- pack weights: [14 pair][3 dh][64 lane] x 16B B-frags ----------------
__global__ void pack_w_kernel(const float* __restrict__ w, uint4* __restrict__ wp) {
    int t = blockIdx.x * 256 + threadIdx.x;
    if (t >= NPAIR * 3 * 64) return;
    int l = t & 63, pd = t >> 6;
    int p = pd / 3, dh = pd % 3;
    int co = l & 15, kh = l >> 4;
    int m = kh >> 1, cih = (kh & 1) * 8;
    int c = 2 * p + m;
    uint_t r[4] = {0, 0, 0, 0};
    if (c <= 26) {
        int tap = c * 3 + dh;   // de*27+df*9+dg*3+dh
        #pragma unroll
        for (int jj = 0; jj < 4; ++jj) {
            ushort_t lo = f2bf(w[(co * 16 + cih + 2 * jj) * 81 + tap]);
            ushort_t hi = f2bf(w[(co * 16 + cih + 2 * jj + 1) * 81 + tap]);
            r[jj] = (uint_t)lo | ((uint_t)hi << 16);
        }
    }
    uint4 q; q.x = r[0]; q.y = r[1]; q.z = r[2]; q.w = r[3];
    wp[t] = q;
}

// ---------------- L1: cin=1 fp32 conv -> padded fp32 [b][pos][16] ----------------
__global__ __launch_bounds__(256) void conv1_kernel(
    const float* __restrict__ in, const float* __restrict__ w,
    const float* __restrict__ bias, float* __restrict__ out) {
    int idx = blockIdx.x * 256 + threadIdx.x;
    if (idx >= 900) return;
    int b = blockIdx.z;
    int co0 = blockIdx.y * 8;
    int g = idx % 9;
    int f = (idx / 9) % 10;
    int e = idx / 90;

    float acc[8][9];
    #pragma unroll
    for (int co = 0; co < 8; ++co) {
        float bv = bias[co0 + co];
        #pragma unroll
        for (int h = 0; h < 9; ++h) acc[co][h] = bv;
    }

    const float* ip = in + (size_t)b * P1POS;
    #pragma unroll
    for (int de = 0; de < 3; ++de)
    #pragma unroll
    for (int df = 0; df < 3; ++df)
    #pragma unroll
    for (int dg = 0; dg < 3; ++dg) {
        const float* rp = ip + ((e + de) * 12 + (f + df)) * P1PLANE + (g + dg) * 11;
        float v[11];
        #pragma unroll
        for (int k = 0; k < 11; ++k) v[k] = rp[k];
        #pragma unroll
        for (int dh = 0; dh < 3; ++dh) {
            int tap = de * 27 + df * 9 + dg * 3 + dh;
            #pragma unroll
            for (int co = 0; co < 8; ++co) {
                float ws = w[(co0 + co) * 81 + tap];
                #pragma unroll
                for (int h = 0; h < 9; ++h)
                    acc[co][h] = fmaf(ws, v[h + dh], acc[co][h]);
            }
        }
    }

    float* op = out + ((size_t)b * P1POS + ((e + 1) * 12 + (f + 1)) * P1PLANE + (g + 1) * 11 + 1) * 16;
    #pragma unroll
    for (int co = 0; co < 8; ++co)
        #pragma unroll
        for (int h = 0; h < 9; ++h)
            op[h * 16 + co0 + co] = fmaxf(acc[co][h], 0.f);
}

// ---------------- MFMA conv: DPP dh-sharing; padded fp32 global in/out ----------------
// block = (b, eb in {0,2,4,6,8}, fb in 0..9); outputs e' = eb+1..eb+2, f' = fb+1.
__global__ __launch_bounds__(384, 2) void conv_mfma_kernel(
    const float* __restrict__ in, const uint4* __restrict__ wp,
    const float* __restrict__ bias, float* __restrict__ out) {

    __shared__ __align__(16) char sIn[LDSTILE];

    int tid = threadIdx.x;
    int b  = blockIdx.y;
    int eb = (blockIdx.x / 10) * 2;
    int fb = blockIdx.x % 10;

    // ---- stage: 2112 positions; zero-fill outside valid region (pads never read from global) ----
    const float* gin = in + (size_t)b * P1POS * 16;
    #pragma unroll 1
    for (int i = tid; i < 12 * 11 * 16; i += 384) {
        int h_l = i & 15;
        int gl_pl = i >> 4;
        int g_l = gl_pl % 11;
        int pl  = gl_pl / 11;
        int pe = pl / 3, pf = pl % 3;
        int e2 = eb + pe;           // e' 0..11
        int f2 = fb + pf;           // f' 0..11
        uint4 q0 = make_uint4(0, 0, 0, 0), q1 = q0;
        if (e2 >= 1 && e2 <= 10 && f2 >= 1 && f2 <= 10 &&
            g_l >= 1 && g_l <= 9 && h_l >= 1 && h_l <= 9) {
            const float4* g4 = (const float4*)(gin + (size_t)((e2 * 12 + f2) * P1PLANE + g_l * 11 + h_l) * 16);
            float4 v0 = g4[0], v1 = g4[1], v2 = g4[2], v3 = g4[3];
            q0.x = pk2(v0.x, v0.y); q0.y = pk2(v0.z, v0.w);
            q0.z = pk2(v1.x, v1.y); q0.w = pk2(v1.z, v1.w);
            q1.x = pk2(v2.x, v2.y); q1.y = pk2(v2.z, v2.w);
            q1.z = pk2(v3.x, v3.y); q1.w = pk2(v3.z, v3.w);
        }
        *(uint4*)(sIn + i * 32)      = q0;
        *(uint4*)(sIn + i * 32 + 16) = q1;
    }
    __syncthreads();

    int l = tid & 63;
    int wv = tid >> 6;                 // 0..5
    int r = l & 15;                    // h row
    int kh = l >> 4;
    int m = kh >> 1;                   // K-pair member (tap select)
    int laneOff = r * 32 + (kh & 1) * 16;

    // 18 tiles (le in 0..1, gg in 0..8); wave handles wv, wv+6, wv+12
    int id1 = wv + 6, id2 = wv + 12;
    int tb0 = (wv  / 9) * (3 * LPLANE) + (wv  % 9) * 512 + laneOff;
    int tb1 = (id1 / 9) * (3 * LPLANE) + (id1 % 9) * 512 + laneOff;
    int tb2 = (id2 / 9) * (3 * LPLANE) + (id2 % 9) * 512 + laneOff;

    float bv = bias[l & 15];
    f32x4 acc0 = {bv, bv, bv, bv}, acc1 = acc0, acc2 = acc0;

    const short8* wv8 = (const short8*)wp;

    #pragma unroll
    for (int p = 0; p < NPAIR; ++p) {
        int c = 2 * p + m; if (c > 26) c = 26;   // dummy member: valid addr, zero weights
        int de = c / 9, df = (c / 3) % 3, dg = c % 3;
        int offp = (de * 3 + df) * LPLANE + dg * 512;

        short8 B0 = wv8[(p * 3 + 0) * 64 + l];
        short8 B1 = wv8[(p * 3 + 1) * 64 + l];
        short8 B2 = wv8[(p * 3 + 2) * 64 + l];

        short8 a1 = *(const short8*)(sIn + tb0 + offp);
        short8 a0 = dpp_shift<0x111>(a1);
        short8 a2 = dpp_shift<0x101>(a1);
        acc0 = __builtin_amdgcn_mfma_f32_16x16x32_bf16(a0, B0, acc0, 0, 0, 0);
        acc0 = __builtin_amdgcn_mfma_f32_16x16x32_bf16(a1, B1, acc0, 0, 0, 0);
        acc0 = __builtin_amdgcn_mfma_f32_16x16x32_bf16(a2, B2, acc0, 0, 0, 0);

        short8 b1f = *(const short8*)(sIn + tb1 + offp);
        short8 b0f = dpp_shift<0x111>(b1f);
        short8 b2f = dpp_shift<0x101>(b1f);
        acc1 = __builtin_amdgcn_mfma_f32_16x16x32_bf16(b0f, B0, acc1, 0, 0, 0);
        acc1 = __builtin_amdgcn_mfma_f32_16x16x32_bf16(b1f, B1, acc1, 0, 0, 0);
        acc1 = __builtin_amdgcn_mfma_f32_16x16x32_bf16(b2f, B2, acc1, 0, 0, 0);

        short8 c1f = *(const short8*)(sIn + tb2 + offp);
        short8 c0f = dpp_shift<0x111>(c1f);
        short8 c2f = dpp_shift<0x101>(c1f);
        acc2 = __builtin_amdgcn_mfma_f32_16x16x32_bf16(c0f, B0, acc2, 0, 0, 0);
        acc2 = __builtin_amdgcn_mfma_f32_16x16x32_bf16(c1f, B1, acc2, 0, 0, 0);
        acc2 = __builtin_amdgcn_mfma_f32_16x16x32_bf16(c2f, B2, acc2, 0, 0, 0);
    }

    // ---- store: D col = lane&15 = co, row = kh*4+reg = h'; keep h' in [1,9] ----
    float* gout = out + (size_t)b * P1POS * 16;
    int co = l & 15;
    {
        int le = wv / 9, gg = wv % 9;
        int base = ((eb + 1 + le) * 12 + (fb + 1)) * P1PLANE + (gg + 1) * 11;
        #pragma unroll
        for (int reg = 0; reg < 4; ++reg) {
            int rr = kh * 4 + reg;
            if (rr >= 1 && rr <= 9) gout[(size_t)(base + rr) * 16 + co] = fmaxf(acc0[reg], 0.f);
        }
    }
    {
        int le = id1 / 9, gg = id1 % 9;
        int base = ((eb + 1 + le) * 12 + (fb + 1)) * P1PLANE + (gg + 1) * 11;
        #pragma unroll
        for (int reg = 0; reg < 4; ++reg) {
            int rr = kh * 4 + reg;
            if (rr >= 1 && rr <= 9) gout[(size_t)(base + rr) * 16 + co] = fmaxf(acc1[reg], 0.f);
        }
    }
    {
        int le = id2 / 9, gg = id2 % 9;
        int base = ((eb + 1 + le) * 12 + (fb + 1)) * P1PLANE + (gg + 1) * 11;
        #pragma unroll
        for (int reg = 0; reg < 4; ++reg) {
            int rr = kh * 4 + reg;
            if (rr >= 1 && rr <= 9) gout[(size_t)(base + rr) * 16 + co] = fmaxf(acc2[reg], 0.f);
        }
    }
}

// ---------------- feat = mean over ef (interior only): fp32 [b][c][81] ----------------
__global__ void feat_kernel(const float* __restrict__ a, float* __restrict__ feat, int nb) {
    int idx = blockIdx.x * 256 + threadIdx.x;
    if (idx >= nb * CH * 81) return;
    int c = idx & 15;
    int gh = (idx >> 4) % 81;
    int b = idx / (81 * 16);
    int g = gh / 9, h = gh % 9;
    const float* ap = a + (size_t)b * P1POS * 16 + ((g + 1) * 11 + (h + 1)) * 16 + c;
    float s = 0.f;
    #pragma unroll
    for (int e = 0; e < 10; ++e)
        #pragma unroll
        for (int f = 0; f < 10; ++f)
            s += ap[(size_t)(((e + 1) * 12 + (f + 1)) * P1PLANE) * 16];
    feat[((size_t)b * CH + c) * 81 + gh] = s * 0.01f;
}

// ---------------- fc ----------------
__global__ void fc_kernel(const float* __restrict__ feat, const float* __restrict__ fcw,
                          const float* __restrict__ fcb, float* __restrict__ out, int nb) {
    int idx = blockIdx.x * 256 + threadIdx.x;
    if (idx >= nb * OUTC * 81) return;
    int s = idx % 81;
    int o = (idx / 81) % OUTC;
    int b = idx / (81 * OUTC);
    const float* fp = feat + (size_t)b * CH * 81 + s;
    float acc = fcb[o];
    #pragma unroll
    for (int c = 0; c < CH; ++c) acc += fcw[o * CH + c] * fp[c * 81];
    out[idx] = acc;
}

extern "C" void kernel_launch(void* const* d_in, const int* in_sizes, int n_in,
                              void* d_out, int out_size, void* d_ws, size_t ws_size,
                              hipStream_t stream) {
    const float* x   = (const float*)d_in[0];
    const float* w1  = (const float*)d_in[1];
    const float* b1  = (const float*)d_in[2];
    const float* w2  = (const float*)d_in[3];
    const float* b2  = (const float*)d_in[4];
    const float* w3  = (const float*)d_in[5];
    const float* b3  = (const float*)d_in[6];
    const float* w4  = (const float*)d_in[7];
    const float* b4  = (const float*)d_in[8];
    const float* w5  = (const float*)d_in[9];
    const float* b5  = (const float*)d_in[10];
    const float* fcw = (const float*)d_in[11];
    const float* fcb = (const float*)d_in[12];
    float* outp = (float*)d_out;

    // ---- ws layout ----
    char* wsc = (char*)d_ws;
    const size_t WPL4 = (size_t)NPAIR * 3 * 64;            // 2688 uint4 per layer
    uint4* wp_all = (uint4*)wsc;
    size_t off = 4 * WPL4 * sizeof(uint4);                  // 172 KB

    const size_t perb_bytes = (size_t)P1POS * 4 + 2ull * P1POS * 16 * 4 + (size_t)CH * 81 * 4;
    size_t avail = (ws_size > off) ? ws_size - off : 0;
    int nbmax = (int)(avail / perb_bytes);
    if (nbmax < 1) nbmax = 1;
    if (nbmax > BB) nbmax = BB;

    float* featb = (float*)(wsc + off); off += (size_t)nbmax * CH * 81 * 4;
    float* bufP  = (float*)(wsc + off); off += (size_t)nbmax * P1POS * 4;
    float* bufA  = (float*)(wsc + off); off += (size_t)nbmax * P1POS * 16 * 4;
    float* bufB  = (float*)(wsc + off);

    // ---- pack weights for L2..L5 ----
    const float* ws_[4] = {w2, w3, w4, w5};
    for (int i = 0; i < 4; ++i)
        pack_w_kernel<<<(int)((NPAIR * 3 * 64 + 255) / 256), 256, 0, stream>>>(ws_[i], wp_all + i * WPL4);

    // ---- zero L1 padded input only (bufA/bufB pads are never read) ----
    hipMemsetAsync(bufP, 0, (size_t)nbmax * P1POS * 4, stream);

    for (int b0 = 0; b0 < BB; b0 += nbmax) {
        int nb = BB - b0;
        if (nb > nbmax) nb = nbmax;

        int pt = nb * NBANDS * 81;
        prep_kernel<<<(pt + 255) / 256, 256, 0, stream>>>(x + (size_t)b0 * NBANDS * 81, bufP, nb);

        dim3 c1g(4, 2, nb);
        conv1_kernel<<<c1g, 256, 0, stream>>>(bufP, w1, b1, bufA);

        dim3 mg(50, nb);
        conv_mfma_kernel<<<mg, 384, 0, stream>>>(bufA, wp_all + 0 * WPL4, b2, bufB);
        conv_mfma_kernel<<<mg, 384, 0, stream>>>(bufB, wp_all + 1 * WPL4, b3, bufA);
        conv_mfma_kernel<<<mg, 384, 0, stream>>>(bufA, wp_all + 2 * WPL4, b4, bufB);
        conv_mfma_kernel<<<mg, 384, 0, stream>>>(bufB, wp_all + 3 * WPL4, b5, bufA);

        int ft = nb * CH * 81;
        feat_kernel<<<(ft + 255) / 256, 256, 0, stream>>>(bufA, featb, nb);

        int ot = nb * OUTC * 81;
        fc_kernel<<<(ot + 255) / 256, 256, 0, stream>>>(featb, fcw, fcb, outp + (size_t)b0 * OUTC * 81, nb);
    }
}

// Round 6
// 693.818 us; speedup vs baseline: 7.1095x; 5.9584x over previous
//
#include <hip/hip_runtime.h>

#define BB 128
#define CH 16
#define NBANDS 100
#define OUTC 10

// padded fp32 activations: [12 e'][12 f'][11 g'][11 h'] x16 ci; valid e',f' in [1,10], g',h' in [1,9]
#define P1PLANE 121
#define P1POS   17424   /* 12*12*121 */

// conv_mfma LDS tile: [24 planes = 4e' x 6f'][11 g][16 h][16 ci bf16] = 135168 B
#define LPLANE  5632        /* 11*16*32 B */
#define NPLANES 24
#define LDSTILE (NPLANES*LPLANE)
#define NKP     5           /* 9 (de,df) combos -> 5 K=32 pairs (last half dummy) */

typedef unsigned short ushort_t;
typedef unsigned int uint_t;
typedef __attribute__((ext_vector_type(8))) short short8;
typedef __attribute__((ext_vector_type(4))) float f32x4;

__device__ __forceinline__ ushort_t f2bf(float f) {
    unsigned u = __float_as_uint(f);
    unsigned r = u + 0x7fffu + ((u >> 16) & 1u);   // RNE
    return (ushort_t)(r >> 16);
}
__device__ __forceinline__ uint_t pk2(float a, float b) {
    return (uint_t)f2bf(a) | ((uint_t)f2bf(b) << 16);
}
// XOR addr bits[8:7] (= h[3:2]) into bits[5:4] (16B-slot): 4-way -> 2-way (free) on both
// the h-strided A-reads and the h-consecutive staging writes.
__device__ __forceinline__ int swz(int x) { return x ^ ((x >> 3) & 0x30); }

// DPP shift within 16-lane rows, bound_ctrl=1 (OOB lanes -> 0).
// row_shr:1 (0x111): dst[n]=src[n-1]; row_shl:1 (0x101): dst[n]=src[n+1]
template<int CTRL>
__device__ __forceinline__ short8 dpp_shift(short8 v) {
    union { short8 s; int i[4]; } a, b;
    a.s = v;
    #pragma unroll
    for (int k = 0; k < 4; ++k)
        b.i[k] = __builtin_amdgcn_update_dpp(0, a.i[k], CTRL, 0xf, 0xf, true);
    return b.s;
}

// ---------------- prep: local = x - center -> padded fp32 single-channel ----------------
__global__ void prep_kernel(const float* __restrict__ x, float* __restrict__ bufP, int nb) {
    int idx = blockIdx.x * 256 + threadIdx.x;
    if (idx >= nb * NBANDS * 81) return;
    int s = idx % 81;
    int p = (idx / 81) % NBANDS;
    int b = idx / (81 * NBANDS);
    int e = p / 10, f = p % 10, g = s / 9, h = s % 9;
    const float* xp = x + ((size_t)b * NBANDS + p) * 81;
    float v = xp[s] - xp[40];
    bufP[(size_t)b * P1POS + ((e + 1) * 12 + (f + 1)) * P1PLANE + (g + 1) * 11 + (h + 1)] = v;
}

// ---------------- pack weights: [5 kp][9 dgdh][64 lane] x 16B B-frags ----------------
// K=32 = 2 (de,df) combos (member m = kh>>1) x 16 ci (half = kh&1). tap = c*9 + dg*3 + dh.
__global__ void pack_w_kernel(const float* __restrict__ w, uint4* __restrict__ wp) {
    int t = blockIdx.x * 256 + threadIdx.x;
    if (t >= NKP * 9 * 64) return;
    int l = t & 63, pd = t >> 6;
    int kp = pd / 9, q = pd % 9;
    int co = l & 15, kh = l >> 4;
    int m = kh >> 1, cih = (kh & 1) * 8;
    int c = 2 * kp + m;
    uint_t r[4] = {0, 0, 0, 0};
    if (c <= 8) {
        int tap = c * 9 + q;     // (de*3+df)*9 + dg*3 + dh = de*27+df*9+dg*3+dh
        #pragma unroll
        for (int jj = 0; jj < 4; ++jj) {
            ushort_t lo = f2bf(w[(co * 16 + cih + 2 * jj) * 81 + tap]);
            ushort_t hi = f2bf(w[(co * 16 + cih + 2 * jj + 1) * 81 + tap]);
            r[jj] = (uint_t)lo | ((uint_t)hi << 16);
        }
    }
    uint4 v; v.x = r[0]; v.y = r[1]; v.z = r[2]; v.w = r[3];
    wp[t] = v;
}

// ---------------- L1: cin=1 fp32 conv -> padded fp32 [b][pos][16] ----------------
__global__ __launch_bounds__(256) void conv1_kernel(
    const float* __restrict__ in, const float* __restrict__ w,
    const float* __restrict__ bias, float* __restrict__ out) {
    int idx = blockIdx.x * 256 + threadIdx.x;
    if (idx >= 900) return;
    int b = blockIdx.z;
    int co0 = blockIdx.y * 8;
    int g = idx % 9;
    int f = (idx / 9) % 10;
    int e = idx / 90;

    float acc[8][9];
    #pragma unroll
    for (int co = 0; co < 8; ++co) {
        float bv = bias[co0 + co];
        #pragma unroll
        for (int h = 0; h < 9; ++h) acc[co][h] = bv;
    }

    const float* ip = in + (size_t)b * P1POS;
    #pragma unroll
    for (int de = 0; de < 3; ++de)
    #pragma unroll
    for (int df = 0; df < 3; ++df)
    #pragma unroll
    for (int dg = 0; dg < 3; ++dg) {
        const float* rp = ip + ((e + de) * 12 + (f + df)) * P1PLANE + (g + dg) * 11;
        float v[11];
        #pragma unroll
        for (int k = 0; k < 11; ++k) v[k] = rp[k];
        #pragma unroll
        for (int dh = 0; dh < 3; ++dh) {
            int tap = de * 27 + df * 9 + dg * 3 + dh;
            #pragma unroll
            for (int co = 0; co < 8; ++co) {
                float ws = w[(co0 + co) * 81 + tap];
                #pragma unroll
                for (int h = 0; h < 9; ++h)
                    acc[co][h] = fmaf(ws, v[h + dh], acc[co][h]);
            }
        }
    }

    float* op = out + ((size_t)b * P1POS + ((e + 1) * 12 + (f + 1)) * P1PLANE + (g + 1) * 11 + 1) * 16;
    #pragma unroll
    for (int co = 0; co < 8; ++co)
        #pragma unroll
        for (int h = 0; h < 9; ++h)
            op[h * 16 + co0 + co] = fmaxf(acc[co][h], 0.f);
}

// ---------------- MFMA conv: 1 LDS row-read -> 9 MFMAs (3 dg x 3 dh-DPP) ----------------
// block = (b, eb in {0,2,4,6,8}, fg in {0,1,2}); 8 waves: wave (we,wf) owns output
// column (e'=eb+1+we, f'=fg*4+wf+1), 9 g-tiles of 16h x 16co.
__global__ __launch_bounds__(512) void conv_mfma_kernel(
    const float* __restrict__ in, const uint4* __restrict__ wp,
    const float* __restrict__ bias, float* __restrict__ out) {

    __shared__ __align__(16) char sIn[LDSTILE];   // 135168 B

    int tid = threadIdx.x;
    int b  = blockIdx.y;
    int eb = (blockIdx.x / 3) * 2;
    int f4 = (blockIdx.x % 3) * 4;

    // ---- stage 24 planes, interior-only reads, zero-fill pads (no global memset needed) ----
    const float* gin = in + (size_t)b * P1POS * 16;
    #pragma unroll 1
    for (int i = tid; i < NPLANES * 176; i += 512) {
        int h = i & 15;
        int g = (i >> 4) % 11;
        int pl = i / 176;
        int pe = pl / 6, pf = pl % 6;
        int e2 = eb + pe, f2 = f4 + pf;
        uint4 q0 = make_uint4(0, 0, 0, 0), q1 = q0;
        if (e2 >= 1 && e2 <= 10 && f2 >= 1 && f2 <= 10 &&
            g >= 1 && g <= 9 && h >= 1 && h <= 9) {
            const float4* g4 = (const float4*)(gin + (size_t)((e2 * 12 + f2) * P1PLANE + g * 11 + h) * 16);
            float4 v0 = g4[0], v1 = g4[1], v2 = g4[2], v3 = g4[3];
            q0.x = pk2(v0.x, v0.y); q0.y = pk2(v0.z, v0.w);
            q0.z = pk2(v1.x, v1.y); q0.w = pk2(v1.z, v1.w);
            q1.x = pk2(v2.x, v2.y); q1.y = pk2(v2.z, v2.w);
            q1.z = pk2(v3.x, v3.y); q1.w = pk2(v3.z, v3.w);
        }
        *(uint4*)(sIn + swz(i * 32))      = q0;
        *(uint4*)(sIn + swz(i * 32 + 16)) = q1;
    }
    __syncthreads();   // the ONLY barrier; LDS is read-only below

    int l = tid & 63, wv = tid >> 6;
    int we = wv >> 2, wf = wv & 3;
    int f_out = f4 + wf + 1;
    if (f_out > 10) return;            // ragged fg=2 block: waves 2,3 idle (post-barrier)
    int e_out = eb + 1 + we;

    int h = l & 15, kh = l >> 4;
    int m = kh >> 1;                   // K-pair member -> which (de,df) plane this lane reads
    int half16 = (kh & 1) * 16;        // ci half within the 32-B row

    float bv = bias[l & 15];
    f32x4 acc[9];
    #pragma unroll
    for (int g9 = 0; g9 < 9; ++g9) acc[g9] = f32x4{bv, bv, bv, bv};

    const short8* wv8 = (const short8*)wp;

    #pragma unroll 1
    for (int kp = 0; kp < NKP; ++kp) {
        int c = 2 * kp + m; if (c > 8) c = 8;   // dummy member: valid plane, zero weights
        int pl = (we + c / 3) * 6 + (wf + c % 3);
        int pbase = pl * LPLANE + h * 32 + half16;

        short8 Bf[9];
        #pragma unroll
        for (int q = 0; q < 9; ++q) Bf[q] = wv8[(kp * 9 + q) * 64 + l];

        #pragma unroll
        for (int gi = 0; gi < 11; ++gi) {
            short8 a1 = *(const short8*)(sIn + swz(pbase + gi * 512));
            short8 a0 = dpp_shift<0x111>(a1);   // in(h-1) -> dh=0
            short8 a2 = dpp_shift<0x101>(a1);   // in(h+1) -> dh=2
            #pragma unroll
            for (int dg = 0; dg < 3; ++dg) {
                int go = gi + 1 - dg;           // compile-time after unroll
                if (go >= 1 && go <= 9) {
                    acc[go - 1] = __builtin_amdgcn_mfma_f32_16x16x32_bf16(a0, Bf[dg * 3 + 0], acc[go - 1], 0, 0, 0);
                    acc[go - 1] = __builtin_amdgcn_mfma_f32_16x16x32_bf16(a1, Bf[dg * 3 + 1], acc[go - 1], 0, 0, 0);
                    acc[go - 1] = __builtin_amdgcn_mfma_f32_16x16x32_bf16(a2, Bf[dg * 3 + 2], acc[go - 1], 0, 0, 0);
                }
            }
        }
    }

    // ---- store: D col = lane&15 = co, row = kh*4+reg = h'; keep h' in [1,9] ----
    float* gout = out + (size_t)b * P1POS * 16;
    int co = l & 15;
    #pragma unroll
    for (int go = 1; go <= 9; ++go) {
        int base = ((e_out * 12 + f_out) * P1PLANE + go * 11) * 16 + co;
        #pragma unroll
        for (int reg = 0; reg < 4; ++reg) {
            int rr = kh * 4 + reg;
            if (rr >= 1 && rr <= 9)
                gout[base + rr * 16] = fmaxf(acc[go - 1][reg], 0.f);
        }
    }
}

// ---------------- feat = mean over ef (interior only): fp32 [b][c][81] ----------------
__global__ void feat_kernel(const float* __restrict__ a, float* __restrict__ feat, int nb) {
    int idx = blockIdx.x * 256 + threadIdx.x;
    if (idx >= nb * CH * 81) return;
    int c = idx & 15;
    int gh = (idx >> 4) % 81;
    int b = idx / (81 * 16);
    int g = gh / 9, h = gh % 9;
    const float* ap = a + (size_t)b * P1POS * 16 + ((g + 1) * 11 + (h + 1)) * 16 + c;
    float s = 0.f;
    #pragma unroll
    for (int e = 0; e < 10; ++e)
        #pragma unroll
        for (int f = 0; f < 10; ++f)
            s += ap[(size_t)(((e + 1) * 12 + (f + 1)) * P1PLANE) * 16];
    feat[((size_t)b * CH + c) * 81 + gh] = s * 0.01f;
}

// ---------------- fc ----------------
__global__ void fc_kernel(const float* __restrict__ feat, const float* __restrict__ fcw,
                          const float* __restrict__ fcb, float* __restrict__ out, int nb) {
    int idx = blockIdx.x * 256 + threadIdx.x;
    if (idx >= nb * OUTC * 81) return;
    int s = idx % 81;
    int o = (idx / 81) % OUTC;
    int b = idx / (81 * OUTC);
    const float* fp = feat + (size_t)b * CH * 81 + s;
    float acc = fcb[o];
    #pragma unroll
    for (int c = 0; c < CH; ++c) acc += fcw[o * CH + c] * fp[c * 81];
    out[idx] = acc;
}

extern "C" void kernel_launch(void* const* d_in, const int* in_sizes, int n_in,
                              void* d_out, int out_size, void* d_ws, size_t ws_size,
                              hipStream_t stream) {
    const float* x   = (const float*)d_in[0];
    const float* w1  = (const float*)d_in[1];
    const float* b1  = (const float*)d_in[2];
    const float* w2  = (const float*)d_in[3];
    const float* b2  = (const float*)d_in[4];
    const float* w3  = (const float*)d_in[5];
    const float* b3  = (const float*)d_in[6];
    const float* w4  = (const float*)d_in[7];
    const float* b4  = (const float*)d_in[8];
    const float* w5  = (const float*)d_in[9];
    const float* b5  = (const float*)d_in[10];
    const float* fcw = (const float*)d_in[11];
    const float* fcb = (const float*)d_in[12];
    float* outp = (float*)d_out;

    // ---- ws layout ----
    char* wsc = (char*)d_ws;
    const size_t WPL4 = (size_t)NKP * 9 * 64;              // 2880 uint4 per layer
    uint4* wp_all = (uint4*)wsc;
    size_t off = 4 * WPL4 * sizeof(uint4);                  // 184 KB

    const size_t perb_bytes = (size_t)P1POS * 4 + 2ull * P1POS * 16 * 4 + (size_t)CH * 81 * 4;
    size_t avail = (ws_size > off) ? ws_size - off : 0;
    int nbmax = (int)(avail / perb_bytes);
    if (nbmax < 1) nbmax = 1;
    if (nbmax > BB) nbmax = BB;

    float* featb = (float*)(wsc + off); off += (size_t)nbmax * CH * 81 * 4;
    float* bufP  = (float*)(wsc + off); off += (size_t)nbmax * P1POS * 4;
    float* bufA  = (float*)(wsc + off); off += (size_t)nbmax * P1POS * 16 * 4;
    float* bufB  = (float*)(wsc + off);

    // ---- pack weights for L2..L5 ----
    const float* ws_[4] = {w2, w3, w4, w5};
    for (int i = 0; i < 4; ++i)
        pack_w_kernel<<<(int)((NKP * 9 * 64 + 255) / 256), 256, 0, stream>>>(ws_[i], wp_all + i * WPL4);

    // ---- zero only the L1 padded single-channel buffer (bufA/bufB pads never read) ----
    hipMemsetAsync(bufP, 0, (size_t)nbmax * P1POS * 4, stream);

    for (int b0 = 0; b0 < BB; b0 += nbmax) {
        int nb = BB - b0;
        if (nb > nbmax) nb = nbmax;

        int pt = nb * NBANDS * 81;
        prep_kernel<<<(pt + 255) / 256, 256, 0, stream>>>(x + (size_t)b0 * NBANDS * 81, bufP, nb);

        dim3 c1g(4, 2, nb);
        conv1_kernel<<<c1g, 256, 0, stream>>>(bufP, w1, b1, bufA);

        dim3 mg(15, nb);
        conv_mfma_kernel<<<mg, 512, 0, stream>>>(bufA, wp_all + 0 * WPL4, b2, bufB);
        conv_mfma_kernel<<<mg, 512, 0, stream>>>(bufB, wp_all + 1 * WPL4, b3, bufA);
        conv_mfma_kernel<<<mg, 512, 0, stream>>>(bufA, wp_all + 2 * WPL4, b4, bufB);
        conv_mfma_kernel<<<mg, 512, 0, stream>>>(bufB, wp_all + 3 * WPL4, b5, bufA);

        int ft = nb * CH * 81;
        feat_kernel<<<(ft + 255) / 256, 256, 0, stream>>>(bufA, featb, nb);

        int ot = nb * OUTC * 81;
        fc_kernel<<<(ot + 255) / 256, 256, 0, stream>>>(featb, fcw, fcb, outp + (size_t)b0 * OUTC * 81, nb);
    }
}

// Round 7
// 600.439 us; speedup vs baseline: 8.2152x; 1.1555x over previous
//
#include <hip/hip_runtime.h>

#define BB 128
#define CH 16
#define NBANDS 100
#define OUTC 10

// padded geometry: [12 e'][12 f'][11 g'][11 h']; valid e',f' in [1,10], g',h' in [1,9]
#define P1PLANE 121
#define P1POS   17424   /* 12*12*121 */

// conv_mfma LDS tile: [24 planes = 4e' x 6f'][11 g][16 h][16 ci bf16] = 135168 B
#define LPLANE  5632        /* 11*16*32 B */
#define NPLANES 24
#define LDSTILE (NPLANES*LPLANE)
#define NKP     5           /* 9 (de,df) combos -> 5 K=32 pairs (last half dummy) */
#define WPL4    (NKP*9*64)  /* uint4 per layer = 2880 */

typedef unsigned short ushort_t;
typedef unsigned int uint_t;
typedef __attribute__((ext_vector_type(8))) short short8;
typedef __attribute__((ext_vector_type(4))) float f32x4;

__device__ __forceinline__ ushort_t f2bf(float f) {
    unsigned u = __float_as_uint(f);
    unsigned r = u + 0x7fffu + ((u >> 16) & 1u);   // RNE
    return (ushort_t)(r >> 16);
}
__device__ __forceinline__ uint_t pk2(float a, float b) {
    return (uint_t)f2bf(a) | ((uint_t)f2bf(b) << 16);
}
// XOR addr bits[8:7] (= h[3:2]) into bits[5:4]: 4-way -> 2-way (free) on A-reads and staging
__device__ __forceinline__ int swz(int x) { return x ^ ((x >> 3) & 0x30); }

// DPP shift within 16-lane rows, bound_ctrl=1 (OOB lanes -> 0).
// row_shr:1 (0x111): dst[n]=src[n-1]; row_shl:1 (0x101): dst[n]=src[n+1]
template<int CTRL>
__device__ __forceinline__ short8 dpp_shift(short8 v) {
    union { short8 s; int i[4]; } a, b;
    a.s = v;
    #pragma unroll
    for (int k = 0; k < 4; ++k)
        b.i[k] = __builtin_amdgcn_update_dpp(0, a.i[k], CTRL, 0xf, 0xf, true);
    return b.s;
}

// ---------------- prep: local = x - center -> padded fp32, zero-fills pads ----------------
__global__ void prep_kernel(const float* __restrict__ x, float* __restrict__ bufP, int nb) {
    int idx = blockIdx.x * 256 + threadIdx.x;
    if (idx >= nb * P1POS) return;
    int pos = idx % P1POS;
    int b = idx / P1POS;
    int e = pos / 1452;
    int r = pos % 1452;
    int f = r / 121;
    int s = r % 121;
    int g = s / 11, h = s % 11;
    float v = 0.f;
    if (e >= 1 && e <= 10 && f >= 1 && f <= 10 && g >= 1 && g <= 9 && h >= 1 && h <= 9) {
        const float* xp = x + ((size_t)b * NBANDS + (e - 1) * 10 + (f - 1)) * 81;
        v = xp[(g - 1) * 9 + (h - 1)] - xp[40];
    }
    bufP[idx] = v;
}

// ---------------- pack weights, all 4 layers: [4][5 kp][9 dgdh][64 lane] x 16B ----------------
__global__ void pack_w_kernel(const float* __restrict__ w2, const float* __restrict__ w3,
                              const float* __restrict__ w4, const float* __restrict__ w5,
                              uint4* __restrict__ wp) {
    int t = blockIdx.x * 256 + threadIdx.x;
    if (t >= WPL4) return;
    int layer = blockIdx.y;
    const float* w = (layer == 0) ? w2 : (layer == 1) ? w3 : (layer == 2) ? w4 : w5;
    int l = t & 63, pd = t >> 6;
    int kp = pd / 9, q = pd % 9;
    int co = l & 15, kh = l >> 4;
    int m = kh >> 1, cih = (kh & 1) * 8;
    int c = 2 * kp + m;
    uint_t r[4] = {0, 0, 0, 0};
    if (c <= 8) {
        int tap = c * 9 + q;     // de*27+df*9+dg*3+dh
        #pragma unroll
        for (int jj = 0; jj < 4; ++jj) {
            ushort_t lo = f2bf(w[(co * 16 + cih + 2 * jj) * 81 + tap]);
            ushort_t hi = f2bf(w[(co * 16 + cih + 2 * jj + 1) * 81 + tap]);
            r[jj] = (uint_t)lo | ((uint_t)hi << 16);
        }
    }
    uint4 v; v.x = r[0]; v.y = r[1]; v.z = r[2]; v.w = r[3];
    wp[(size_t)layer * WPL4 + t] = v;
}

// ---------------- L1: cin=1 fp32 conv -> padded bf16 [b][pos][16] ----------------
__global__ __launch_bounds__(256) void conv1_kernel(
    const float* __restrict__ in, const float* __restrict__ w,
    const float* __restrict__ bias, ushort_t* __restrict__ out) {
    int idx = blockIdx.x * 256 + threadIdx.x;
    if (idx >= 900) return;
    int b = blockIdx.z;
    int co0 = blockIdx.y * 8;
    int g = idx % 9;
    int f = (idx / 9) % 10;
    int e = idx / 90;

    float acc[8][9];
    #pragma unroll
    for (int co = 0; co < 8; ++co) {
        float bv = bias[co0 + co];
        #pragma unroll
        for (int h = 0; h < 9; ++h) acc[co][h] = bv;
    }

    const float* ip = in + (size_t)b * P1POS;
    #pragma unroll
    for (int de = 0; de < 3; ++de)
    #pragma unroll
    for (int df = 0; df < 3; ++df)
    #pragma unroll
    for (int dg = 0; dg < 3; ++dg) {
        const float* rp = ip + ((e + de) * 12 + (f + df)) * P1PLANE + (g + dg) * 11;
        float v[11];
        #pragma unroll
        for (int k = 0; k < 11; ++k) v[k] = rp[k];
        #pragma unroll
        for (int dh = 0; dh < 3; ++dh) {
            int tap = de * 27 + df * 9 + dg * 3 + dh;
            #pragma unroll
            for (int co = 0; co < 8; ++co) {
                float ws = w[(co0 + co) * 81 + tap];
                #pragma unroll
                for (int h = 0; h < 9; ++h)
                    acc[co][h] = fmaf(ws, v[h + dh], acc[co][h]);
            }
        }
    }

    // store 8 co packed as uint4 (16B) per h position
    ushort_t* op = out + ((size_t)b * P1POS + ((e + 1) * 12 + (f + 1)) * P1PLANE + (g + 1) * 11 + 1) * 16 + co0;
    #pragma unroll
    for (int h = 0; h < 9; ++h) {
        uint4 q;
        q.x = pk2(fmaxf(acc[0][h], 0.f), fmaxf(acc[1][h], 0.f));
        q.y = pk2(fmaxf(acc[2][h], 0.f), fmaxf(acc[3][h], 0.f));
        q.z = pk2(fmaxf(acc[4][h], 0.f), fmaxf(acc[5][h], 0.f));
        q.w = pk2(fmaxf(acc[6][h], 0.f), fmaxf(acc[7][h], 0.f));
        *(uint4*)(op + h * 16) = q;
    }
}

// ---------------- MFMA conv: 1 LDS row-read -> 9 MFMAs; bf16 global in/out ----------------
// block = (b, eb in {0,2,4,6,8}, fg in {0,1,2}); wave (we,wf) owns column (eb+1+we, fg*4+wf+1)
__global__ __launch_bounds__(512) void conv_mfma_kernel(
    const ushort_t* __restrict__ in, const uint4* __restrict__ wp,
    const float* __restrict__ bias, ushort_t* __restrict__ out) {

    __shared__ __align__(16) char sIn[LDSTILE];   // 135168 B

    int tid = threadIdx.x;
    int b  = blockIdx.y;
    int eb = (blockIdx.x / 3) * 2;
    int f4 = (blockIdx.x % 3) * 4;

    // ---- stage 24 planes: pure uint4 copy (no conversion), zero-fill pads ----
    const ushort_t* gin = in + (size_t)b * P1POS * 16;
    #pragma unroll 1
    for (int i = tid; i < NPLANES * 176; i += 512) {
        int h = i & 15;
        int gp = i >> 4;
        int g = gp % 11;
        int pl = gp / 11;
        int pe = pl / 6, pf = pl % 6;
        int e2 = eb + pe, f2 = f4 + pf;
        uint4 q0 = make_uint4(0, 0, 0, 0), q1 = q0;
        if (e2 >= 1 && e2 <= 10 && f2 >= 1 && f2 <= 10 &&
            g >= 1 && g <= 9 && h >= 1 && h <= 9) {
            const uint4* g4 = (const uint4*)(gin + (size_t)((e2 * 12 + f2) * P1PLANE + g * 11 + h) * 16);
            q0 = g4[0]; q1 = g4[1];
        }
        *(uint4*)(sIn + swz(i * 32))      = q0;
        *(uint4*)(sIn + swz(i * 32 + 16)) = q1;
    }
    __syncthreads();   // the ONLY barrier

    int l = tid & 63, wv = tid >> 6;
    int we = wv >> 2, wf = wv & 3;
    int f_out = f4 + wf + 1;
    if (f_out > 10) return;            // ragged fg=2 block
    int e_out = eb + 1 + we;

    int h = l & 15, kh = l >> 4;
    int m = kh >> 1;                   // K-pair member -> (de,df) select
    int half16 = (kh & 1) * 16;        // ci half within the 32-B row

    float bv = bias[l & 15];
    f32x4 acc[9];
    #pragma unroll
    for (int g9 = 0; g9 < 9; ++g9) acc[g9] = f32x4{bv, bv, bv, bv};

    const short8* wv8 = (const short8*)wp;

    #pragma unroll 1
    for (int kp = 0; kp < NKP; ++kp) {
        int c = 2 * kp + m; if (c > 8) c = 8;   // dummy member: valid plane, zero weights
        int pl = (we + c / 3) * 6 + (wf + c % 3);
        int pbase = pl * LPLANE + h * 32 + half16;

        short8 Bf[9];
        #pragma unroll
        for (int q = 0; q < 9; ++q) Bf[q] = wv8[(kp * 9 + q) * 64 + l];

        #pragma unroll
        for (int gi = 0; gi < 11; ++gi) {
            short8 a1 = *(const short8*)(sIn + swz(pbase + gi * 512));
            short8 a0 = dpp_shift<0x111>(a1);   // in(h-1) -> dh=0
            short8 a2 = dpp_shift<0x101>(a1);   // in(h+1) -> dh=2
            #pragma unroll
            for (int dg = 0; dg < 3; ++dg) {
                int go = gi + 1 - dg;           // compile-time after unroll
                if (go >= 1 && go <= 9) {
                    acc[go - 1] = __builtin_amdgcn_mfma_f32_16x16x32_bf16(a0, Bf[dg * 3 + 0], acc[go - 1], 0, 0, 0);
                    acc[go - 1] = __builtin_amdgcn_mfma_f32_16x16x32_bf16(a1, Bf[dg * 3 + 1], acc[go - 1], 0, 0, 0);
                    acc[go - 1] = __builtin_amdgcn_mfma_f32_16x16x32_bf16(a2, Bf[dg * 3 + 2], acc[go - 1], 0, 0, 0);
                }
            }
        }
    }

    // ---- store: D col = lane&15 = co, row = kh*4+reg = h'; keep h' in [1,9] ----
    ushort_t* gout = out + (size_t)b * P1POS * 16;
    int co = l & 15;
    #pragma unroll
    for (int go = 1; go <= 9; ++go) {
        int base = ((e_out * 12 + f_out) * P1PLANE + go * 11) * 16 + co;
        #pragma unroll
        for (int reg = 0; reg < 4; ++reg) {
            int rr = kh * 4 + reg;
            if (rr >= 1 && rr <= 9)
                gout[base + rr * 16] = f2bf(fmaxf(acc[go - 1][reg], 0.f));
        }
    }
}

// ---------------- fused feat(mean over ef) + fc: bf16 acts -> fp32 out ----------------
__global__ void featfc_kernel(const ushort_t* __restrict__ a, const float* __restrict__ fcw,
                              const float* __restrict__ fcb, float* __restrict__ out, int nb) {
    int idx = blockIdx.x * 256 + threadIdx.x;
    if (idx >= nb * 81) return;
    int gh = idx % 81;
    int b = idx / 81;
    int g = gh / 9, h = gh % 9;
    const uint_t* ap = (const uint_t*)(a + (size_t)b * P1POS * 16) + (size_t)((g + 1) * 11 + (h + 1)) * 8;

    float fs[16];
    #pragma unroll
    for (int c = 0; c < 16; ++c) fs[c] = 0.f;

    #pragma unroll 1
    for (int e = 1; e <= 10; ++e) {
        #pragma unroll
        for (int f = 1; f <= 10; ++f) {
            const uint4* p = (const uint4*)(ap + (size_t)(e * 12 + f) * P1PLANE * 8);
            uint4 u0 = p[0], u1 = p[1];
            uint_t u[8] = {u0.x, u0.y, u0.z, u0.w, u1.x, u1.y, u1.z, u1.w};
            #pragma unroll
            for (int j = 0; j < 8; ++j) {
                fs[2 * j]     += __uint_as_float(u[j] << 16);
                fs[2 * j + 1] += __uint_as_float(u[j] & 0xffff0000u);
            }
        }
    }

    #pragma unroll
    for (int o = 0; o < OUTC; ++o) {
        float acc = fcb[o];
        #pragma unroll
        for (int c = 0; c < 16; ++c) acc = fmaf(fcw[o * 16 + c], fs[c] * 0.01f, acc);
        out[((size_t)b * OUTC + o) * 81 + gh] = acc;
    }
}

extern "C" void kernel_launch(void* const* d_in, const int* in_sizes, int n_in,
                              void* d_out, int out_size, void* d_ws, size_t ws_size,
                              hipStream_t stream) {
    const float* x   = (const float*)d_in[0];
    const float* w1  = (const float*)d_in[1];
    const float* b1  = (const float*)d_in[2];
    const float* w2  = (const float*)d_in[3];
    const float* b2  = (const float*)d_in[4];
    const float* w3  = (const float*)d_in[5];
    const float* b3  = (const float*)d_in[6];
    const float* w4  = (const float*)d_in[7];
    const float* b4  = (const float*)d_in[8];
    const float* w5  = (const float*)d_in[9];
    const float* b5  = (const float*)d_in[10];
    const float* fcw = (const float*)d_in[11];
    const float* fcb = (const float*)d_in[12];
    float* outp = (float*)d_out;

    // ---- ws layout ----
    char* wsc = (char*)d_ws;
    uint4* wp_all = (uint4*)wsc;
    size_t off = 4ull * WPL4 * sizeof(uint4);                  // 184 KB

    // per-batch: bufP fp32 (69.7KB) + 2 bf16 act buffers (557.6KB each)
    const size_t perb_bytes = (size_t)P1POS * 4 + 2ull * P1POS * 16 * 2;
    size_t avail = (ws_size > off) ? ws_size - off : 0;
    int nbmax = (int)(avail / perb_bytes);
    if (nbmax < 1) nbmax = 1;
    if (nbmax > BB) nbmax = BB;

    float* bufP = (float*)(wsc + off);     off += (size_t)nbmax * P1POS * 4;
    ushort_t* bufA = (ushort_t*)(wsc + off); off += (size_t)nbmax * P1POS * 16 * 2;
    ushort_t* bufB = (ushort_t*)(wsc + off);

    // ---- pack weights for L2..L5 (single launch) ----
    dim3 pg((WPL4 + 255) / 256, 4);
    pack_w_kernel<<<pg, 256, 0, stream>>>(w2, w3, w4, w5, wp_all);

    for (int b0 = 0; b0 < BB; b0 += nbmax) {
        int nb = BB - b0;
        if (nb > nbmax) nb = nbmax;

        int pt = nb * P1POS;
        prep_kernel<<<(pt + 255) / 256, 256, 0, stream>>>(x + (size_t)b0 * NBANDS * 81, bufP, nb);

        dim3 c1g(4, 2, nb);
        conv1_kernel<<<c1g, 256, 0, stream>>>(bufP, w1, b1, bufA);

        dim3 mg(15, nb);
        conv_mfma_kernel<<<mg, 512, 0, stream>>>(bufA, wp_all + 0 * WPL4, b2, bufB);
        conv_mfma_kernel<<<mg, 512, 0, stream>>>(bufB, wp_all + 1 * WPL4, b3, bufA);
        conv_mfma_kernel<<<mg, 512, 0, stream>>>(bufA, wp_all + 2 * WPL4, b4, bufB);
        conv_mfma_kernel<<<mg, 512, 0, stream>>>(bufB, wp_all + 3 * WPL4, b5, bufA);

        int ft = nb * 81;
        featfc_kernel<<<(ft + 255) / 256, 256, 0, stream>>>(bufA, fcw, fcb, outp + (size_t)b0 * OUTC * 81, nb);
    }
}